// Round 6
// baseline (479.981 us; speedup 1.0000x reference)
//
#include <hip/hip_runtime.h>

// PointNet 3-NN feature interpolation, v5: exact 3-NN via spatial binning.
// bin_count  : histogram points into 16^3 cells (per batch).
// bin_scan   : exclusive prefix sum -> cell base offsets (+cursor copy).
// bin_scatter: counting-sort points into cell-ordered {2x,2y,2z,norm} + idx.
// knn3_grid  : per-query ring scan (27-cell ring1, shell expansion w/ exact
//              stopping bound), lexicographic (d,idx) top-3, weights.
// interp     : per-(b,d) row staged in LDS, gather+weighted-sum.

constexpr int   GD    = 16;
constexpr float GORG  = -4.0f;
constexpr float GINVH = 2.0f;     // 1/h, h = 0.5
constexpr float GH    = 0.5f;
constexpr int   NCELL = GD * GD * GD;  // 4096
constexpr float DINF  = 3.4e38f;
constexpr int   ISENT = 0x7fffffff;

__device__ __forceinline__ int cellOf(float x) {
    int c = (int)floorf((x - GORG) * GINVH);
    return min(GD - 1, max(0, c));
}

__global__ __launch_bounds__(256)
void bin_count(const float* __restrict__ xyz1, int* __restrict__ cnt,
               int B, int N)
{
    int t = blockIdx.x * 256 + threadIdx.x;
    if (t >= B * N) return;
    int b = t / N, n = t - b * N;
    const float* __restrict__ bx = xyz1 + (size_t)b * 3 * N;
    int cx = cellOf(bx[n]), cy = cellOf(bx[N + n]), cz = cellOf(bx[2 * N + n]);
    atomicAdd(&cnt[b * NCELL + (cz * GD + cy) * GD + cx], 1);
}

__global__ __launch_bounds__(256)
void bin_scan(const int* __restrict__ cnt, int* __restrict__ base,
              int* __restrict__ cursor)
{
    __shared__ int part[256];
    const int b   = blockIdx.x;
    const int tid = threadIdx.x;
    const int* __restrict__ c = cnt + b * NCELL;
    int* __restrict__ bs = base + b * NCELL;
    int* __restrict__ cu = cursor + b * NCELL;

    int loc[16];
    int sum = 0;
#pragma unroll
    for (int i = 0; i < 16; ++i) { loc[i] = sum; sum += c[tid * 16 + i]; }
    part[tid] = sum;
    __syncthreads();
    for (int off = 1; off < 256; off <<= 1) {
        int v = (tid >= off) ? part[tid - off] : 0;
        __syncthreads();
        part[tid] += v;
        __syncthreads();
    }
    int excl = tid ? part[tid - 1] : 0;
#pragma unroll
    for (int i = 0; i < 16; ++i) {
        int v = excl + loc[i];
        bs[tid * 16 + i] = v;
        cu[tid * 16 + i] = v;
    }
}

__global__ __launch_bounds__(256)
void bin_scatter(const float* __restrict__ xyz1, int* __restrict__ cursor,
                 float4* __restrict__ spt, int* __restrict__ sidx,
                 int B, int N)
{
#pragma clang fp contract(off)
    int t = blockIdx.x * 256 + threadIdx.x;
    if (t >= B * N) return;
    int b = t / N, n = t - b * N;
    const float* __restrict__ bx = xyz1 + (size_t)b * 3 * N;
    float x = bx[n], y = bx[N + n], z = bx[2 * N + n];
    int cid = (cellOf(z) * GD + cellOf(y)) * GD + cellOf(x);
    int slot = atomicAdd(&cursor[b * NCELL + cid], 1);
    // {2x,2y,2z,norm}: pre-doubled coords (pow2-exact); norm in np sum order.
    spt[(size_t)b * N + slot] = make_float4(x + x, y + y, z + z,
                                            (x * x + y * y) + z * z);
    sidx[(size_t)b * N + slot] = n;
}

__global__ __launch_bounds__(64)
void knn3_grid(const float4* __restrict__ spt, const int* __restrict__ sidx,
               const float* __restrict__ xyz2,
               const int* __restrict__ base, const int* __restrict__ cnt,
               int B, int N, int S,
               int* __restrict__ idx0, int* __restrict__ idx1,
               int* __restrict__ idx2,
               float* __restrict__ w0, float* __restrict__ w1,
               float* __restrict__ w2)
{
#pragma clang fp contract(off)
    const int q = blockIdx.x * 64 + threadIdx.x;
    const int b = q / S, s = q - b * S;
    const float* __restrict__ q2p = xyz2 + (size_t)b * 3 * S;
    const float qx = q2p[s];
    const float qy = q2p[S + s];
    const float qz = q2p[2 * S + s];
    const float qss = (qx * qx + qy * qy) + qz * qz;
    const int cx = cellOf(qx), cy = cellOf(qy), cz = cellOf(qz);

    const float4* __restrict__ sp = spt + (size_t)b * N;
    const int* __restrict__ si = sidx + (size_t)b * N;
    const int* __restrict__ bb = base + b * NCELL;
    const int* __restrict__ bc = cnt + b * NCELL;

    float d0 = DINF, d1 = DINF, d2 = DINF;
    int   i0 = ISENT, i1 = ISENT, i2 = ISENT;

    // contiguous-range scan with lexicographic (d, idx) top-3 insert:
    // order-independent, matches top_k lowest-index tie-breaking exactly.
    auto scanRange = [&](int lo, int hi) {
        for (int j = lo; j < hi; ++j) {
            float4 p = sp[j];
            int ix = si[j];
            float dot2 = (qx * p.x + qy * p.y) + qz * p.z;  // == 2*dot, exact
            float d = (qss + p.w) - dot2;
            bool l2 = (d < d2) || (d == d2 && ix < i2);
            if (l2) {
                bool l1 = (d < d1) || (d == d1 && ix < i1);
                bool l0 = (d < d0) || (d == d0 && ix < i0);
                d2 = l1 ? d1 : d;  i2 = l1 ? i1 : ix;
                d1 = l0 ? d0 : (l1 ? d : d1);
                i1 = l0 ? i0 : (l1 ? ix : i1);
                d0 = l0 ? d : d0;  i0 = l0 ? ix : i0;
            }
        }
    };
    // one row of cells (zz, yy, xlo..xhi): consecutive cids -> one sorted range
    auto scanRow = [&](int zz, int yy, int xlo, int xhi) {
        if ((unsigned)zz >= (unsigned)GD || (unsigned)yy >= (unsigned)GD) return;
        xlo = max(0, xlo); xhi = min(GD - 1, xhi);
        if (xlo > xhi) return;
        int cfirst = (zz * GD + yy) * GD + xlo;
        int clast  = (zz * GD + yy) * GD + xhi;
        scanRange(bb[cfirst], bb[clast] + bc[clast]);
    };

    // rings 0+1: 9 contiguous rows
    for (int dz = -1; dz <= 1; ++dz)
        for (int dy = -1; dy <= 1; ++dy)
            scanRow(cz + dz, cy + dy, cx - 1, cx + 1);

    // shell expansion with exact stopping bound:
    // points outside completed Chebyshev ring R are >= (R*h)^2 away.
    int R = 1;
    while (true) {
        float bnd = (float)R * GH;
        if (d2 < bnd * bnd) break;     // strict: outside points can't tie-win
        ++R;
        if (R > 2 * GD) break;          // whole grid certainly scanned
        for (int dz = -R; dz <= R; ++dz) {
            int adz = dz < 0 ? -dz : dz;
            for (int dy = -R; dy <= R; ++dy) {
                int ady = dy < 0 ? -dy : dy;
                if (adz == R || ady == R) {
                    scanRow(cz + dz, cy + dy, cx - R, cx + R);
                } else {
                    scanRow(cz + dz, cy + dy, cx - R, cx - R);
                    scanRow(cz + dz, cy + dy, cx + R, cx + R);
                }
            }
        }
    }

    const float r0 = 1.0f / (d0 + 1e-8f);
    const float r1 = 1.0f / (d1 + 1e-8f);
    const float r2 = 1.0f / (d2 + 1e-8f);
    const float sum = (r0 + r1) + r2;          // np sum order
    idx0[q] = i0; idx1[q] = i1; idx2[q] = i2;
    w0[q] = r0 / sum; w1[q] = r1 / sum; w2[q] = r2 / sum;
}

__global__ __launch_bounds__(256)
void interp_kernel(const float* __restrict__ points1,
                   const int* __restrict__ idx0, const int* __restrict__ idx1,
                   const int* __restrict__ idx2,
                   const float* __restrict__ w0, const float* __restrict__ w1,
                   const float* __restrict__ w2,
                   float* __restrict__ out, int N, int S, int D)
{
#pragma clang fp contract(off)
    __shared__ float row[8192];
    const int bd = blockIdx.x;
    const int b  = bd / D;
    const float* __restrict__ src = points1 + (size_t)bd * N;

    for (int i = threadIdx.x * 4; i < N; i += blockDim.x * 4) {
        *reinterpret_cast<float4*>(&row[i]) =
            *reinterpret_cast<const float4*>(src + i);
    }
    __syncthreads();

    float* __restrict__ dst = out + (size_t)bd * S;
    const int qb = b * S;
    for (int s = threadIdx.x; s < S; s += blockDim.x) {
        int q = qb + s;
        float a = row[idx0[q]] * w0[q];
        float c = row[idx1[q]] * w1[q];
        float e = row[idx2[q]] * w2[q];
        dst[s] = (a + c) + e;
    }
}

extern "C" void kernel_launch(void* const* d_in, const int* in_sizes, int n_in,
                              void* d_out, int out_size, void* d_ws, size_t ws_size,
                              hipStream_t stream) {
    const float* xyz1    = (const float*)d_in[0];
    const float* xyz2    = (const float*)d_in[1];
    const float* points1 = (const float*)d_in[2];
    float* out = (float*)d_out;

    const int B = 8;
    const int N = in_sizes[0] / (3 * B);
    const int S = in_sizes[1] / (3 * B);
    const int D = in_sizes[2] / (B * N);
    const int BS = B * S;

    // ws layout (16B-aligned first): sorted float4, then int/float arrays.
    float4* spt  = (float4*)d_ws;
    int*    sidx = (int*)(spt + (size_t)B * N);
    int*    cnt  = sidx + (size_t)B * N;
    int*    base = cnt + (size_t)B * NCELL;
    int*    cur  = base + (size_t)B * NCELL;
    int*    idx0 = cur + (size_t)B * NCELL;
    int*    idx1 = idx0 + BS;
    int*    idx2 = idx1 + BS;
    float*  w0   = (float*)(idx2 + BS);
    float*  w1   = w0 + BS;
    float*  w2   = w1 + BS;

    hipMemsetAsync(cnt, 0, (size_t)B * NCELL * sizeof(int), stream);

    bin_count<<<(B * N + 255) / 256, 256, 0, stream>>>(xyz1, cnt, B, N);
    bin_scan<<<B, 256, 0, stream>>>(cnt, base, cur);
    bin_scatter<<<(B * N + 255) / 256, 256, 0, stream>>>(xyz1, cur, spt, sidx, B, N);

    knn3_grid<<<BS / 64, 64, 0, stream>>>(spt, sidx, xyz2, base, cnt,
                                          B, N, S,
                                          idx0, idx1, idx2, w0, w1, w2);

    interp_kernel<<<B * D, 256, 0, stream>>>(points1, idx0, idx1, idx2,
                                             w0, w1, w2, out, N, S, D);
}

// Round 7
// 125.798 us; speedup vs baseline: 3.8155x; 3.8155x over previous
//
#include <hip/hip_runtime.h>

// PointNet 3-NN feature interpolation, v7: two-stage threshold, LDS-staged.
// knn3_seed : chunks 0..3 (2048 pts), running-top3 scan -> per-chunk partials.
// tau3_merge: tau[q] = 3rd-smallest distance over first 2048 points.
// knn3_main : chunks 4..15, filter (d <= tau) -> rare masked insert, partials.
// knn3_merge: merge 16 per-chunk top-3s (exact, ascending order), weights.
// interp    : per-(b,d) row staged in LDS, gather+weighted-sum.

constexpr int QT = 256;        // queries (=threads) per block in knn phases
constexpr int CS = 512;        // points per chunk
constexpr int NCHUNK = 16;     // 8192 / 512
constexpr int SEEDC  = 4;      // seed chunks (2048 points)
constexpr float DINF = 3.4e38f;

__device__ __forceinline__ void insert3b(float& d0, float& d1, float& d2,
                                         int& i0, int& i1, int& i2,
                                         float d, int n) {
    bool c0 = d < d0, c1 = d < d1, c2 = d < d2;
    float nd2 = c1 ? d1 : (c2 ? d : d2);
    int   ni2 = c1 ? i1 : (c2 ? n : i2);
    float nd1 = c0 ? d0 : (c1 ? d : d1);
    int   ni1 = c0 ? i0 : (c1 ? n : i1);
    float nd0 = c0 ? d  : d0;
    int   ni0 = c0 ? n  : i0;
    d0 = nd0; d1 = nd1; d2 = nd2;
    i0 = ni0; i1 = ni1; i2 = ni2;
}

// insert knowing d < d2
__device__ __forceinline__ void insert3_hit(float& d0, float& d1, float& d2,
                                            int& i0, int& i1, int& i2,
                                            float d, int n) {
    bool c0 = d < d0, c1 = d < d1;
    float nd0 = c0 ? d  : d0;
    float nd1 = c0 ? d0 : (c1 ? d : d1);
    float nd2 = c1 ? d1 : d;
    int   ni0 = c0 ? n  : i0;
    int   ni1 = c0 ? i0 : (c1 ? n : i1);
    int   ni2 = c1 ? i1 : n;
    d0 = nd0; d1 = nd1; d2 = nd2;
    i0 = ni0; i1 = ni1; i2 = ni2;
}

// Stage CS points as {2x, 2y, 2z, norm}: 2x exact (pow2); (qx*2x+qy*2y)+qz*2z
// rounds bit-identically to 2*((qx*x+qy*y)+qz*z); norm in np sum order.
__device__ __forceinline__ void stage_chunk(float4* spt,
                                            const float* __restrict__ bx,
                                            int N, int tid) {
#pragma clang fp contract(off)
    const float* __restrict__ by = bx + N;
    const float* __restrict__ bz = by + N;
    for (int i = tid * 4; i < CS; i += QT * 4) {
        float4 vx = *reinterpret_cast<const float4*>(bx + i);
        float4 vy = *reinterpret_cast<const float4*>(by + i);
        float4 vz = *reinterpret_cast<const float4*>(bz + i);
        spt[i + 0] = make_float4(vx.x + vx.x, vy.x + vy.x, vz.x + vz.x,
                                 (vx.x*vx.x + vy.x*vy.x) + vz.x*vz.x);
        spt[i + 1] = make_float4(vx.y + vx.y, vy.y + vy.y, vz.y + vz.y,
                                 (vx.y*vx.y + vy.y*vy.y) + vz.y*vz.y);
        spt[i + 2] = make_float4(vx.z + vx.z, vy.z + vy.z, vz.z + vz.z,
                                 (vx.z*vx.z + vy.z*vy.z) + vz.z*vz.z);
        spt[i + 3] = make_float4(vx.w + vx.w, vy.w + vy.w, vz.w + vz.w,
                                 (vx.w*vx.w + vy.w*vy.w) + vz.w*vz.w);
    }
}

__global__ __launch_bounds__(256)
void knn3_seed(const float* __restrict__ xyz1, const float* __restrict__ xyz2,
               int B, int N, int S, int BS,
               float* __restrict__ pd0, float* __restrict__ pd1,
               float* __restrict__ pd2,
               int* __restrict__ pi0, int* __restrict__ pi1,
               int* __restrict__ pi2)
{
#pragma clang fp contract(off)
    __shared__ float4 spt[CS];
    const int tid = threadIdx.x;
    const int q   = blockIdx.x * QT + tid;
    const int c   = blockIdx.y;               // 0..SEEDC-1
    const int b   = q / S;                    // QT | S -> uniform per block
    const int s   = q - b * S;
    const int n0  = c * CS;

    stage_chunk(spt, xyz1 + (size_t)b * 3 * N + n0, N, tid);
    __syncthreads();

    const float* __restrict__ q2p = xyz2 + (size_t)b * 3 * S;
    const float qx = q2p[s];
    const float qy = q2p[S + s];
    const float qz = q2p[2 * S + s];
    const float qss = (qx * qx + qy * qy) + qz * qz;

    float d0 = DINF, d1 = DINF, d2 = DINF;
    int   i0 = 0, i1 = 0, i2 = 0;
#pragma unroll 4
    for (int k = 0; k < CS; ++k) {
        float4 p = spt[k];
        float dot2 = (qx * p.x + qy * p.y) + qz * p.z;   // == 2*dot, exact
        float d    = (qss + p.w) - dot2;
        if (d < d2)                       // guard ≡ no-op case of insert3b
            insert3_hit(d0, d1, d2, i0, i1, i2, d, n0 + k);
    }
    const size_t off = (size_t)c * BS + q;
    pd0[off] = d0; pd1[off] = d1; pd2[off] = d2;
    pi0[off] = i0; pi1[off] = i1; pi2[off] = i2;
}

__global__ __launch_bounds__(256)
void tau3_merge(const float* __restrict__ pd0, const float* __restrict__ pd1,
                const float* __restrict__ pd2, int BS,
                float* __restrict__ tau)
{
    const int q = blockIdx.x * 256 + threadIdx.x;
    if (q >= BS) return;
    float d0 = DINF, d1 = DINF, d2 = DINF;
#pragma unroll
    for (int c = 0; c < SEEDC; ++c) {
        const size_t off = (size_t)c * BS + q;
        float a0 = pd0[off], a1 = pd1[off], a2 = pd2[off];
        // value-only top-3 insert (ties irrelevant for the threshold value)
        {   bool c0 = a0 < d0, c1 = a0 < d1, c2 = a0 < d2;
            float n2 = c1 ? d1 : (c2 ? a0 : d2);
            float n1 = c0 ? d0 : (c1 ? a0 : d1);
            d0 = c0 ? a0 : d0; d1 = n1; d2 = n2; }
        {   bool c0 = a1 < d0, c1 = a1 < d1, c2 = a1 < d2;
            float n2 = c1 ? d1 : (c2 ? a1 : d2);
            float n1 = c0 ? d0 : (c1 ? a1 : d1);
            d0 = c0 ? a1 : d0; d1 = n1; d2 = n2; }
        {   bool c0 = a2 < d0, c1 = a2 < d1, c2 = a2 < d2;
            float n2 = c1 ? d1 : (c2 ? a2 : d2);
            float n1 = c0 ? d0 : (c1 ? a2 : d1);
            d0 = c0 ? a2 : d0; d1 = n1; d2 = n2; }
    }
    tau[q] = d2;
}

__global__ __launch_bounds__(256)
void knn3_main(const float* __restrict__ xyz1, const float* __restrict__ xyz2,
               const float* __restrict__ tau,
               int B, int N, int S, int BS,
               float* __restrict__ pd0, float* __restrict__ pd1,
               float* __restrict__ pd2,
               int* __restrict__ pi0, int* __restrict__ pi1,
               int* __restrict__ pi2)
{
#pragma clang fp contract(off)
    __shared__ float4 spt[CS];
    const int tid = threadIdx.x;
    const int q   = blockIdx.x * QT + tid;
    const int c   = blockIdx.y + SEEDC;       // 4..15
    const int b   = q / S;
    const int s   = q - b * S;
    const int n0  = c * CS;

    stage_chunk(spt, xyz1 + (size_t)b * 3 * N + n0, N, tid);
    __syncthreads();

    const float* __restrict__ q2p = xyz2 + (size_t)b * 3 * S;
    const float qx = q2p[s];
    const float qy = q2p[S + s];
    const float qz = q2p[2 * S + s];
    const float qss = (qx * qx + qy * qy) + qz * qz;
    const float t0  = tau[q];

    float d0 = DINF, d1 = DINF, d2 = DINF;
    int   i0 = 0, i1 = 0, i2 = 0;
#pragma unroll 4
    for (int k = 0; k < CS; ++k) {
        float4 p = spt[k];
        float dot2 = (qx * p.x + qy * p.y) + qz * p.z;   // == 2*dot, exact
        float d    = (qss + p.w) - dot2;
        if (__builtin_expect(d <= t0, 0))    // keeps tau-ties; ~9% wave-taken
            insert3b(d0, d1, d2, i0, i1, i2, d, n0 + k);
    }
    const size_t off = (size_t)c * BS + q;
    pd0[off] = d0; pd1[off] = d1; pd2[off] = d2;
    pi0[off] = i0; pi1[off] = i1; pi2[off] = i2;
}

__global__ __launch_bounds__(256)
void knn3_merge(const float* __restrict__ pd0, const float* __restrict__ pd1,
                const float* __restrict__ pd2,
                const int* __restrict__ pi0, const int* __restrict__ pi1,
                const int* __restrict__ pi2,
                int BS,
                int* __restrict__ idx0, int* __restrict__ idx1, int* __restrict__ idx2,
                float* __restrict__ w0, float* __restrict__ w1, float* __restrict__ w2)
{
#pragma clang fp contract(off)
    const int q = blockIdx.x * 256 + threadIdx.x;
    if (q >= BS) return;
    float d0 = DINF, d1 = DINF, d2 = DINF;
    int   i0 = 0, i1 = 0, i2 = 0;
    // ascending chunk order + strict-< insertion == top_k lowest-index ties
    for (int c = 0; c < NCHUNK; ++c) {
        const size_t off = (size_t)c * BS + q;
        insert3b(d0, d1, d2, i0, i1, i2, pd0[off], pi0[off]);
        insert3b(d0, d1, d2, i0, i1, i2, pd1[off], pi1[off]);
        insert3b(d0, d1, d2, i0, i1, i2, pd2[off], pi2[off]);
    }
    const float r0 = 1.0f / (d0 + 1e-8f);
    const float r1 = 1.0f / (d1 + 1e-8f);
    const float r2 = 1.0f / (d2 + 1e-8f);
    const float sum = (r0 + r1) + r2;            // np sum order
    idx0[q] = i0; idx1[q] = i1; idx2[q] = i2;
    w0[q] = r0 / sum; w1[q] = r1 / sum; w2[q] = r2 / sum;
}

__global__ __launch_bounds__(256)
void interp_kernel(const float* __restrict__ points1,
                   const int* __restrict__ idx0, const int* __restrict__ idx1,
                   const int* __restrict__ idx2,
                   const float* __restrict__ w0, const float* __restrict__ w1,
                   const float* __restrict__ w2,
                   float* __restrict__ out, int N, int S, int D)
{
#pragma clang fp contract(off)
    __shared__ float row[8192];
    const int bd = blockIdx.x;
    const int b  = bd / D;
    const float* __restrict__ src = points1 + (size_t)bd * N;

    for (int i = threadIdx.x * 4; i < N; i += blockDim.x * 4) {
        *reinterpret_cast<float4*>(&row[i]) =
            *reinterpret_cast<const float4*>(src + i);
    }
    __syncthreads();

    float* __restrict__ dst = out + (size_t)bd * S;
    const int qb = b * S;
    for (int s = threadIdx.x; s < S; s += blockDim.x) {
        int q = qb + s;
        float a = row[idx0[q]] * w0[q];
        float c = row[idx1[q]] * w1[q];
        float e = row[idx2[q]] * w2[q];
        dst[s] = (a + c) + e;             // np sum order
    }
}

extern "C" void kernel_launch(void* const* d_in, const int* in_sizes, int n_in,
                              void* d_out, int out_size, void* d_ws, size_t ws_size,
                              hipStream_t stream) {
    const float* xyz1    = (const float*)d_in[0];
    const float* xyz2    = (const float*)d_in[1];
    const float* points1 = (const float*)d_in[2];
    float* out = (float*)d_out;

    const int B = 8;
    const int N = in_sizes[0] / (3 * B);
    const int S = in_sizes[1] / (3 * B);
    const int D = in_sizes[2] / (B * N);
    const int BS = B * S;

    float* pd0 = (float*)d_ws;
    float* pd1 = pd0 + (size_t)NCHUNK * BS;
    float* pd2 = pd1 + (size_t)NCHUNK * BS;
    int*   pi0 = (int*)(pd2 + (size_t)NCHUNK * BS);
    int*   pi1 = pi0 + (size_t)NCHUNK * BS;
    int*   pi2 = pi1 + (size_t)NCHUNK * BS;
    int*   idx0 = pi2 + (size_t)NCHUNK * BS;
    int*   idx1 = idx0 + BS;
    int*   idx2 = idx1 + BS;
    float* w0   = (float*)(idx2 + BS);
    float* w1   = w0 + BS;
    float* w2   = w1 + BS;
    float* tau  = w2 + BS;

    // Seed: chunks 0..3, 64x4 = 256 blocks.
    dim3 gs(BS / QT, SEEDC);
    knn3_seed<<<gs, QT, 0, stream>>>(xyz1, xyz2, B, N, S, BS,
                                     pd0, pd1, pd2, pi0, pi1, pi2);

    tau3_merge<<<(BS + 255) / 256, 256, 0, stream>>>(pd0, pd1, pd2, BS, tau);

    // Main: chunks 4..15, 64x12 = 768 blocks (3 blocks/CU).
    dim3 gm(BS / QT, NCHUNK - SEEDC);
    knn3_main<<<gm, QT, 0, stream>>>(xyz1, xyz2, tau, B, N, S, BS,
                                     pd0, pd1, pd2, pi0, pi1, pi2);

    knn3_merge<<<(BS + 255) / 256, 256, 0, stream>>>(pd0, pd1, pd2, pi0, pi1, pi2,
                                                     BS,
                                                     idx0, idx1, idx2, w0, w1, w2);

    interp_kernel<<<B * D, 256, 0, stream>>>(points1, idx0, idx1, idx2,
                                             w0, w1, w2, out, N, S, D);
}

// Round 8
// 119.944 us; speedup vs baseline: 4.0017x; 1.0488x over previous
//
#include <hip/hip_runtime.h>

// PointNet 3-NN feature interpolation, v8.
// knn3_seed : pts 0..1023 in 8 sub-chunks of 128 (grid 64x8, 2 blocks/CU),
//             running-guard top-3 -> partial slots 0..7.
// tau3_merge: tau[q] = 3rd-smallest over first 1024 pts (merge 8 partials).
// knn3_main : pts 1024.., chunks of 512, Q=2 queries/thread, filter d<=tau,
//             partial slots 8.. (GRP groups per block if ws is tight).
// knn3_merge: merge all partial top-3s (ascending order), weights.
// interp    : per-(b,d) row staged in LDS, gather+weighted-sum.

constexpr int QT    = 256;   // threads per block
constexpr int SCS   = 128;   // seed sub-chunk points
constexpr int SEEDP = 1024;  // seed points total
constexpr int SEEDSUB = SEEDP / SCS;  // 8
constexpr int MCS   = 512;   // main points per partial group
constexpr float DINF = 3.4e38f;

__device__ __forceinline__ void insert3b(float& d0, float& d1, float& d2,
                                         int& i0, int& i1, int& i2,
                                         float d, int n) {
    bool c0 = d < d0, c1 = d < d1, c2 = d < d2;
    float nd2 = c1 ? d1 : (c2 ? d : d2);
    int   ni2 = c1 ? i1 : (c2 ? n : i2);
    float nd1 = c0 ? d0 : (c1 ? d : d1);
    int   ni1 = c0 ? i0 : (c1 ? n : i1);
    float nd0 = c0 ? d  : d0;
    int   ni0 = c0 ? n  : i0;
    d0 = nd0; d1 = nd1; d2 = nd2;
    i0 = ni0; i1 = ni1; i2 = ni2;
}

// insert knowing d < d2 (guard established) — identical result to insert3b
__device__ __forceinline__ void insert3_hit(float& d0, float& d1, float& d2,
                                            int& i0, int& i1, int& i2,
                                            float d, int n) {
    bool c0 = d < d0, c1 = d < d1;
    float nd0 = c0 ? d  : d0;
    float nd1 = c0 ? d0 : (c1 ? d : d1);
    float nd2 = c1 ? d1 : d;
    int   ni0 = c0 ? n  : i0;
    int   ni1 = c0 ? i0 : (c1 ? n : i1);
    int   ni2 = c1 ? i1 : n;
    d0 = nd0; d1 = nd1; d2 = nd2;
    i0 = ni0; i1 = ni1; i2 = ni2;
}

// Stage cs pts as {2x,2y,2z,norm}: 2x exact (pow2); (qx*2x+qy*2y)+qz*2z rounds
// bit-identically to 2*((qx*x+qy*y)+qz*z); norm in np sum order.
__device__ __forceinline__ void stage_chunk(float4* spt,
                                            const float* __restrict__ bx,
                                            int N, int cs, int tid) {
#pragma clang fp contract(off)
    const float* __restrict__ by = bx + N;
    const float* __restrict__ bz = by + N;
    for (int i = tid * 4; i < cs; i += QT * 4) {
        float4 vx = *reinterpret_cast<const float4*>(bx + i);
        float4 vy = *reinterpret_cast<const float4*>(by + i);
        float4 vz = *reinterpret_cast<const float4*>(bz + i);
        spt[i + 0] = make_float4(vx.x + vx.x, vy.x + vy.x, vz.x + vz.x,
                                 (vx.x*vx.x + vy.x*vy.x) + vz.x*vz.x);
        spt[i + 1] = make_float4(vx.y + vx.y, vy.y + vy.y, vz.y + vz.y,
                                 (vx.y*vx.y + vy.y*vy.y) + vz.y*vz.y);
        spt[i + 2] = make_float4(vx.z + vx.z, vy.z + vy.z, vz.z + vz.z,
                                 (vx.z*vx.z + vy.z*vy.z) + vz.z*vz.z);
        spt[i + 3] = make_float4(vx.w + vx.w, vy.w + vy.w, vz.w + vz.w,
                                 (vx.w*vx.w + vy.w*vy.w) + vz.w*vz.w);
    }
}

__global__ __launch_bounds__(256)
void knn3_seed(const float* __restrict__ xyz1, const float* __restrict__ xyz2,
               int B, int N, int S, int BS,
               float* __restrict__ pd0, float* __restrict__ pd1,
               float* __restrict__ pd2,
               int* __restrict__ pi0, int* __restrict__ pi1,
               int* __restrict__ pi2)
{
#pragma clang fp contract(off)
    __shared__ float4 spt[SCS];
    const int tid = threadIdx.x;
    const int q   = blockIdx.x * QT + tid;
    const int c   = blockIdx.y;               // 0..SEEDSUB-1
    const int b   = q / S;                    // QT | S
    const int s   = q - b * S;
    const int n0  = c * SCS;

    stage_chunk(spt, xyz1 + (size_t)b * 3 * N + n0, N, SCS, tid);
    __syncthreads();

    const float* __restrict__ q2p = xyz2 + (size_t)b * 3 * S;
    const float qx = q2p[s];
    const float qy = q2p[S + s];
    const float qz = q2p[2 * S + s];
    const float qss = (qx * qx + qy * qy) + qz * qz;

    float d0 = DINF, d1 = DINF, d2 = DINF;
    int   i0 = 0, i1 = 0, i2 = 0;
#pragma unroll 4
    for (int k = 0; k < SCS; ++k) {
        float4 p = spt[k];
        float dot2 = (qx * p.x + qy * p.y) + qz * p.z;   // == 2*dot, exact
        float d    = (qss + p.w) - dot2;
        if (d < d2)                           // guard ≡ no-op case of insert3b
            insert3_hit(d0, d1, d2, i0, i1, i2, d, n0 + k);
    }
    const size_t off = (size_t)c * BS + q;
    pd0[off] = d0; pd1[off] = d1; pd2[off] = d2;
    pi0[off] = i0; pi1[off] = i1; pi2[off] = i2;
}

__global__ __launch_bounds__(256)
void tau3_merge(const float* __restrict__ pd0, const float* __restrict__ pd1,
                const float* __restrict__ pd2, int BS,
                float* __restrict__ tau)
{
    const int q = blockIdx.x * 256 + threadIdx.x;
    if (q >= BS) return;
    float d0 = DINF, d1 = DINF, d2 = DINF;
#pragma unroll
    for (int c = 0; c < SEEDSUB; ++c) {
        const size_t off = (size_t)c * BS + q;
        float a0 = pd0[off], a1 = pd1[off], a2 = pd2[off];
        {   bool c0 = a0 < d0, c1 = a0 < d1, c2 = a0 < d2;
            float n2 = c1 ? d1 : (c2 ? a0 : d2);
            float n1 = c0 ? d0 : (c1 ? a0 : d1);
            d0 = c0 ? a0 : d0; d1 = n1; d2 = n2; }
        {   bool c0 = a1 < d0, c1 = a1 < d1, c2 = a1 < d2;
            float n2 = c1 ? d1 : (c2 ? a1 : d2);
            float n1 = c0 ? d0 : (c1 ? a1 : d1);
            d0 = c0 ? a1 : d0; d1 = n1; d2 = n2; }
        {   bool c0 = a2 < d0, c1 = a2 < d1, c2 = a2 < d2;
            float n2 = c1 ? d1 : (c2 ? a2 : d2);
            float n1 = c0 ? d0 : (c1 ? a2 : d1);
            d0 = c0 ? a2 : d0; d1 = n1; d2 = n2; }
    }
    tau[q] = d2;
}

// Q=2: block covers 2*QT queries; each staged point read once, used twice.
__global__ __launch_bounds__(256)
void knn3_main(const float* __restrict__ xyz1, const float* __restrict__ xyz2,
               const float* __restrict__ tau,
               int B, int N, int S, int BS, int GRP,
               float* __restrict__ pd0, float* __restrict__ pd1,
               float* __restrict__ pd2,
               int* __restrict__ pi0, int* __restrict__ pi1,
               int* __restrict__ pi2)
{
#pragma clang fp contract(off)
    __shared__ float4 spt[MCS];
    const int tid = threadIdx.x;
    const int q0  = blockIdx.x * (2 * QT) + tid;
    const int q1  = q0 + QT;
    const int b   = q0 / S;                   // 512 | S -> uniform per block
    const int s0  = q0 - b * S;

    const float* __restrict__ q2p = xyz2 + (size_t)b * 3 * S;
    const float qx0 = q2p[s0],          qx1 = q2p[s0 + QT];
    const float qy0 = q2p[S + s0],      qy1 = q2p[S + s0 + QT];
    const float qz0 = q2p[2 * S + s0],  qz1 = q2p[2 * S + s0 + QT];
    const float qss0 = (qx0 * qx0 + qy0 * qy0) + qz0 * qz0;
    const float qss1 = (qx1 * qx1 + qy1 * qy1) + qz1 * qz1;
    const float t0 = tau[q0];
    const float t1 = tau[q1];

    for (int g = 0; g < GRP; ++g) {
        const int slot = SEEDSUB + blockIdx.y * GRP + g;
        const int n0   = SEEDP + (slot - SEEDSUB) * MCS;

        stage_chunk(spt, xyz1 + (size_t)b * 3 * N + n0, N, MCS, tid);
        __syncthreads();

        float d00 = DINF, d01 = DINF, d02 = DINF;
        float d10 = DINF, d11 = DINF, d12 = DINF;
        int   i00 = 0, i01 = 0, i02 = 0;
        int   i10 = 0, i11 = 0, i12 = 0;

#pragma unroll 4
        for (int k = 0; k < MCS; ++k) {
            float4 p = spt[k];
            float dota = (qx0 * p.x + qy0 * p.y) + qz0 * p.z;
            float da   = (qss0 + p.w) - dota;
            float dotb = (qx1 * p.x + qy1 * p.y) + qz1 * p.z;
            float db   = (qss1 + p.w) - dotb;
            if (__builtin_expect(da <= t0, 0))
                insert3b(d00, d01, d02, i00, i01, i02, da, n0 + k);
            if (__builtin_expect(db <= t1, 0))
                insert3b(d10, d11, d12, i10, i11, i12, db, n0 + k);
        }
        const size_t offA = (size_t)slot * BS + q0;
        const size_t offB = (size_t)slot * BS + q1;
        pd0[offA] = d00; pd1[offA] = d01; pd2[offA] = d02;
        pi0[offA] = i00; pi1[offA] = i01; pi2[offA] = i02;
        pd0[offB] = d10; pd1[offB] = d11; pd2[offB] = d12;
        pi0[offB] = i10; pi1[offB] = i11; pi2[offB] = i12;
        if (g + 1 < GRP) __syncthreads();     // protect spt before restage
    }
}

__global__ __launch_bounds__(256)
void knn3_merge(const float* __restrict__ pd0, const float* __restrict__ pd1,
                const float* __restrict__ pd2,
                const int* __restrict__ pi0, const int* __restrict__ pi1,
                const int* __restrict__ pi2,
                int nPart, int BS,
                int* __restrict__ idx0, int* __restrict__ idx1, int* __restrict__ idx2,
                float* __restrict__ w0, float* __restrict__ w1, float* __restrict__ w2)
{
#pragma clang fp contract(off)
    const int q = blockIdx.x * 256 + threadIdx.x;
    if (q >= BS) return;
    float d0 = DINF, d1 = DINF, d2 = DINF;
    int   i0 = 0, i1 = 0, i2 = 0;
    // ascending point-index order + strict-< == top_k lowest-index ties
    for (int c = 0; c < nPart; ++c) {
        const size_t off = (size_t)c * BS + q;
        insert3b(d0, d1, d2, i0, i1, i2, pd0[off], pi0[off]);
        insert3b(d0, d1, d2, i0, i1, i2, pd1[off], pi1[off]);
        insert3b(d0, d1, d2, i0, i1, i2, pd2[off], pi2[off]);
    }
    const float r0 = 1.0f / (d0 + 1e-8f);
    const float r1 = 1.0f / (d1 + 1e-8f);
    const float r2 = 1.0f / (d2 + 1e-8f);
    const float sum = (r0 + r1) + r2;            // np sum order
    idx0[q] = i0; idx1[q] = i1; idx2[q] = i2;
    w0[q] = r0 / sum; w1[q] = r1 / sum; w2[q] = r2 / sum;
}

__global__ __launch_bounds__(256)
void interp_kernel(const float* __restrict__ points1,
                   const int* __restrict__ idx0, const int* __restrict__ idx1,
                   const int* __restrict__ idx2,
                   const float* __restrict__ w0, const float* __restrict__ w1,
                   const float* __restrict__ w2,
                   float* __restrict__ out, int N, int S, int D)
{
#pragma clang fp contract(off)
    __shared__ float row[8192];
    const int bd = blockIdx.x;
    const int b  = bd / D;
    const float* __restrict__ src = points1 + (size_t)bd * N;

    for (int i = threadIdx.x * 4; i < N; i += blockDim.x * 4) {
        *reinterpret_cast<float4*>(&row[i]) =
            *reinterpret_cast<const float4*>(src + i);
    }
    __syncthreads();

    float* __restrict__ dst = out + (size_t)bd * S;
    const int qb = b * S;
    for (int s = threadIdx.x; s < S; s += blockDim.x) {
        int q = qb + s;
        float a = row[idx0[q]] * w0[q];
        float c = row[idx1[q]] * w1[q];
        float e = row[idx2[q]] * w2[q];
        dst[s] = (a + c) + e;             // np sum order
    }
}

extern "C" void kernel_launch(void* const* d_in, const int* in_sizes, int n_in,
                              void* d_out, int out_size, void* d_ws, size_t ws_size,
                              hipStream_t stream) {
    const float* xyz1    = (const float*)d_in[0];
    const float* xyz2    = (const float*)d_in[1];
    const float* points1 = (const float*)d_in[2];
    float* out = (float*)d_out;

    const int B = 8;
    const int N = in_sizes[0] / (3 * B);
    const int S = in_sizes[1] / (3 * B);
    const int D = in_sizes[2] / (B * N);
    const int BS = B * S;

    const int nMainGroups = (N - SEEDP) / MCS;   // 14 for N=8192
    int GRP = 1;
    auto wsNeed = [&](int nPart) {
        return (size_t)nPart * BS * 6 * 4 + (size_t)BS * 7 * 4;
    };
    if (wsNeed(SEEDSUB + nMainGroups) > ws_size) GRP = 2;
    const int nPart = SEEDSUB + nMainGroups;     // partial slots (layout)

    float* pd0 = (float*)d_ws;
    float* pd1 = pd0 + (size_t)nPart * BS;
    float* pd2 = pd1 + (size_t)nPart * BS;
    int*   pi0 = (int*)(pd2 + (size_t)nPart * BS);
    int*   pi1 = pi0 + (size_t)nPart * BS;
    int*   pi2 = pi1 + (size_t)nPart * BS;
    int*   idx0 = pi2 + (size_t)nPart * BS;
    int*   idx1 = idx0 + BS;
    int*   idx2 = idx1 + BS;
    float* w0   = (float*)(idx2 + BS);
    float* w1   = w0 + BS;
    float* w2   = w1 + BS;
    float* tau  = w2 + BS;

    // Seed: 8 sub-chunks x 64 query-tiles = 512 blocks (2/CU).
    dim3 gs(BS / QT, SEEDSUB);
    knn3_seed<<<gs, QT, 0, stream>>>(xyz1, xyz2, B, N, S, BS,
                                     pd0, pd1, pd2, pi0, pi1, pi2);

    tau3_merge<<<(BS + 255) / 256, 256, 0, stream>>>(pd0, pd1, pd2, BS, tau);

    // Main: Q=2 -> 32 query-tiles x (14/GRP) groups.
    dim3 gm(BS / (2 * QT), nMainGroups / GRP);
    knn3_main<<<gm, QT, 0, stream>>>(xyz1, xyz2, tau, B, N, S, BS, GRP,
                                     pd0, pd1, pd2, pi0, pi1, pi2);

    knn3_merge<<<(BS + 255) / 256, 256, 0, stream>>>(pd0, pd1, pd2, pi0, pi1, pi2,
                                                     nPart, BS,
                                                     idx0, idx1, idx2, w0, w1, w2);

    interp_kernel<<<B * D, 256, 0, stream>>>(points1, idx0, idx1, idx2,
                                             w0, w1, w2, out, N, S, D);
}

// Round 10
// 87.309 us; speedup vs baseline: 5.4975x; 1.3738x over previous
//
#include <hip/hip_runtime.h>

// PointNet 3-NN feature interpolation, v9.
// knn3_tau  : d-only top-3 over pts 0..1023 (16 sub-chunks of 64, grid 64x16).
// tau3_merge: tau[q] = 3rd-smallest over the 16 sub-chunk partials.
// knn3_main : ALL 16 chunks of 512, filter d<=tau, prefetch-pipelined loop,
//             indexed partials -> slots 0..15.
// knn3_merge: merge 16 partial top-3s (ascending order), weights.
// interp    : per-(b,d) row staged in LDS, gather+weighted-sum.

constexpr int QT     = 256;   // threads per block (knn phases)
constexpr int SCS    = 64;    // tau sub-chunk points
constexpr int NSUB   = 16;    // tau sub-chunks (seed range = 1024 pts)
constexpr int MCS    = 512;   // main chunk points
constexpr int NCHUNK = 16;    // main chunks (all of N)
constexpr float DINF = 3.4e38f;

__device__ __forceinline__ void insert3b(float& d0, float& d1, float& d2,
                                         int& i0, int& i1, int& i2,
                                         float d, int n) {
    bool c0 = d < d0, c1 = d < d1, c2 = d < d2;
    float nd2 = c1 ? d1 : (c2 ? d : d2);
    int   ni2 = c1 ? i1 : (c2 ? n : i2);
    float nd1 = c0 ? d0 : (c1 ? d : d1);
    int   ni1 = c0 ? i0 : (c1 ? n : i1);
    float nd0 = c0 ? d  : d0;
    int   ni0 = c0 ? n  : i0;
    d0 = nd0; d1 = nd1; d2 = nd2;
    i0 = ni0; i1 = ni1; i2 = ni2;
}

// value-only top-3 insert (ties irrelevant for threshold)
__device__ __forceinline__ void insert3v(float& d0, float& d1, float& d2,
                                         float d) {
    bool c0 = d < d0, c1 = d < d1, c2 = d < d2;
    float n2 = c1 ? d1 : (c2 ? d : d2);
    float n1 = c0 ? d0 : (c1 ? d : d1);
    d0 = c0 ? d : d0; d1 = n1; d2 = n2;
}

// Stage cs pts as {2x,2y,2z,norm}: 2x exact (pow2); (qx*2x+qy*2y)+qz*2z rounds
// bit-identically to 2*((qx*x+qy*y)+qz*z); norm in np sum order.
__device__ __forceinline__ void stage_chunk(float4* spt,
                                            const float* __restrict__ bx,
                                            int N, int cs, int tid) {
#pragma clang fp contract(off)
    const float* __restrict__ by = bx + N;
    const float* __restrict__ bz = by + N;
    for (int i = tid * 4; i < cs; i += QT * 4) {
        float4 vx = *reinterpret_cast<const float4*>(bx + i);
        float4 vy = *reinterpret_cast<const float4*>(by + i);
        float4 vz = *reinterpret_cast<const float4*>(bz + i);
        spt[i + 0] = make_float4(vx.x + vx.x, vy.x + vy.x, vz.x + vz.x,
                                 (vx.x*vx.x + vy.x*vy.x) + vz.x*vz.x);
        spt[i + 1] = make_float4(vx.y + vx.y, vy.y + vy.y, vz.y + vz.y,
                                 (vx.y*vx.y + vy.y*vy.y) + vz.y*vz.y);
        spt[i + 2] = make_float4(vx.z + vx.z, vy.z + vy.z, vz.z + vz.z,
                                 (vx.z*vx.z + vy.z*vy.z) + vz.z*vz.z);
        spt[i + 3] = make_float4(vx.w + vx.w, vy.w + vy.w, vz.w + vz.w,
                                 (vx.w*vx.w + vy.w*vy.w) + vz.w*vz.w);
    }
}

__global__ __launch_bounds__(256)
void knn3_tau(const float* __restrict__ xyz1, const float* __restrict__ xyz2,
              int B, int N, int S, int BS,
              float* __restrict__ sd0, float* __restrict__ sd1,
              float* __restrict__ sd2)
{
#pragma clang fp contract(off)
    __shared__ float4 spt[SCS];
    const int tid = threadIdx.x;
    const int q   = blockIdx.x * QT + tid;
    const int c   = blockIdx.y;               // 0..NSUB-1
    const int b   = q / S;                    // QT | S
    const int s   = q - b * S;
    const int n0  = c * SCS;

    stage_chunk(spt, xyz1 + (size_t)b * 3 * N + n0, N, SCS, tid);
    __syncthreads();

    const float* __restrict__ q2p = xyz2 + (size_t)b * 3 * S;
    const float qx = q2p[s];
    const float qy = q2p[S + s];
    const float qz = q2p[2 * S + s];
    const float qss = (qx * qx + qy * qy) + qz * qz;

    float d0 = DINF, d1 = DINF, d2 = DINF;
#pragma unroll 8
    for (int k = 0; k < SCS; ++k) {
        float4 p = spt[k];
        float dot2 = (qx * p.x + qy * p.y) + qz * p.z;   // == 2*dot, exact
        float d    = (qss + p.w) - dot2;
        insert3v(d0, d1, d2, d);
    }
    const size_t off = (size_t)c * BS + q;
    sd0[off] = d0; sd1[off] = d1; sd2[off] = d2;
}

__global__ __launch_bounds__(256)
void tau3_merge(const float* __restrict__ sd0, const float* __restrict__ sd1,
                const float* __restrict__ sd2, int BS,
                float* __restrict__ tau)
{
    const int q = blockIdx.x * 256 + threadIdx.x;
    if (q >= BS) return;
    float d0 = DINF, d1 = DINF, d2 = DINF;
#pragma unroll
    for (int c = 0; c < NSUB; ++c) {
        const size_t off = (size_t)c * BS + q;
        insert3v(d0, d1, d2, sd0[off]);
        insert3v(d0, d1, d2, sd1[off]);
        insert3v(d0, d1, d2, sd2[off]);
    }
    tau[q] = d2;
}

__global__ __launch_bounds__(256)
void knn3_main(const float* __restrict__ xyz1, const float* __restrict__ xyz2,
               const float* __restrict__ tau,
               int B, int N, int S, int BS,
               float* __restrict__ pd0, float* __restrict__ pd1,
               float* __restrict__ pd2,
               int* __restrict__ pi0, int* __restrict__ pi1,
               int* __restrict__ pi2)
{
#pragma clang fp contract(off)
    __shared__ float4 spt[MCS];
    const int tid = threadIdx.x;
    const int q   = blockIdx.x * QT + tid;
    const int c   = blockIdx.y;               // 0..NCHUNK-1
    const int b   = q / S;                    // QT | S
    const int s   = q - b * S;
    const int n0  = c * MCS;

    stage_chunk(spt, xyz1 + (size_t)b * 3 * N + n0, N, MCS, tid);
    __syncthreads();

    const float* __restrict__ q2p = xyz2 + (size_t)b * 3 * S;
    const float qx = q2p[s];
    const float qy = q2p[S + s];
    const float qz = q2p[2 * S + s];
    const float qss = (qx * qx + qy * qy) + qz * qz;
    const float t0  = tau[q];

    float d0 = DINF, d1 = DINF, d2 = DINF;
    int   i0 = 0, i1 = 0, i2 = 0;

    // hand-pipelined: compute group k while group k+4 loads (8 float4 live)
    float4 pa = spt[0], pb = spt[1], pc = spt[2], pd_ = spt[3];
    int k = 0;
    for (; k + 4 < MCS; k += 4) {
        float4 na = spt[k + 4];
        float4 nb = spt[k + 5];
        float4 nc = spt[k + 6];
        float4 nd = spt[k + 7];
        float da = (qss + pa.w) - ((qx * pa.x + qy * pa.y) + qz * pa.z);
        float db = (qss + pb.w) - ((qx * pb.x + qy * pb.y) + qz * pb.z);
        float dc = (qss + pc.w) - ((qx * pc.x + qy * pc.y) + qz * pc.z);
        float dd = (qss + pd_.w) - ((qx * pd_.x + qy * pd_.y) + qz * pd_.z);
        if (__builtin_expect(da <= t0, 0))
            insert3b(d0, d1, d2, i0, i1, i2, da, n0 + k);
        if (__builtin_expect(db <= t0, 0))
            insert3b(d0, d1, d2, i0, i1, i2, db, n0 + k + 1);
        if (__builtin_expect(dc <= t0, 0))
            insert3b(d0, d1, d2, i0, i1, i2, dc, n0 + k + 2);
        if (__builtin_expect(dd <= t0, 0))
            insert3b(d0, d1, d2, i0, i1, i2, dd, n0 + k + 3);
        pa = na; pb = nb; pc = nc; pd_ = nd;
    }
    {   // last group (k == MCS-4)
        float da = (qss + pa.w) - ((qx * pa.x + qy * pa.y) + qz * pa.z);
        float db = (qss + pb.w) - ((qx * pb.x + qy * pb.y) + qz * pb.z);
        float dc = (qss + pc.w) - ((qx * pc.x + qy * pc.y) + qz * pc.z);
        float dd = (qss + pd_.w) - ((qx * pd_.x + qy * pd_.y) + qz * pd_.z);
        if (__builtin_expect(da <= t0, 0))
            insert3b(d0, d1, d2, i0, i1, i2, da, n0 + k);
        if (__builtin_expect(db <= t0, 0))
            insert3b(d0, d1, d2, i0, i1, i2, db, n0 + k + 1);
        if (__builtin_expect(dc <= t0, 0))
            insert3b(d0, d1, d2, i0, i1, i2, dc, n0 + k + 2);
        if (__builtin_expect(dd <= t0, 0))
            insert3b(d0, d1, d2, i0, i1, i2, dd, n0 + k + 3);
    }

    const size_t off = (size_t)c * BS + q;
    pd0[off] = d0; pd1[off] = d1; pd2[off] = d2;
    pi0[off] = i0; pi1[off] = i1; pi2[off] = i2;
}

__global__ __launch_bounds__(256)
void knn3_merge(const float* __restrict__ pd0, const float* __restrict__ pd1,
                const float* __restrict__ pd2,
                const int* __restrict__ pi0, const int* __restrict__ pi1,
                const int* __restrict__ pi2,
                int BS,
                int* __restrict__ idx0, int* __restrict__ idx1, int* __restrict__ idx2,
                float* __restrict__ w0, float* __restrict__ w1, float* __restrict__ w2)
{
#pragma clang fp contract(off)
    const int q = blockIdx.x * 256 + threadIdx.x;
    if (q >= BS) return;
    float d0 = DINF, d1 = DINF, d2 = DINF;
    int   i0 = 0, i1 = 0, i2 = 0;
    // ascending point-range order + strict-< == top_k lowest-index ties
    for (int c = 0; c < NCHUNK; ++c) {
        const size_t off = (size_t)c * BS + q;
        insert3b(d0, d1, d2, i0, i1, i2, pd0[off], pi0[off]);
        insert3b(d0, d1, d2, i0, i1, i2, pd1[off], pi1[off]);
        insert3b(d0, d1, d2, i0, i1, i2, pd2[off], pi2[off]);
    }
    const float r0 = 1.0f / (d0 + 1e-8f);
    const float r1 = 1.0f / (d1 + 1e-8f);
    const float r2 = 1.0f / (d2 + 1e-8f);
    const float sum = (r0 + r1) + r2;            // np sum order
    idx0[q] = i0; idx1[q] = i1; idx2[q] = i2;
    w0[q] = r0 / sum; w1[q] = r1 / sum; w2[q] = r2 / sum;
}

__global__ __launch_bounds__(256)
void interp_kernel(const float* __restrict__ points1,
                   const int* __restrict__ idx0, const int* __restrict__ idx1,
                   const int* __restrict__ idx2,
                   const float* __restrict__ w0, const float* __restrict__ w1,
                   const float* __restrict__ w2,
                   float* __restrict__ out, int N, int S, int D)
{
#pragma clang fp contract(off)
    __shared__ float row[8192];
    const int bd = blockIdx.x;
    const int b  = bd / D;
    const float* __restrict__ src = points1 + (size_t)bd * N;

    for (int i = threadIdx.x * 4; i < N; i += blockDim.x * 4) {
        *reinterpret_cast<float4*>(&row[i]) =
            *reinterpret_cast<const float4*>(src + i);
    }
    __syncthreads();

    float* __restrict__ dst = out + (size_t)bd * S;
    const int qb = b * S;
    for (int s = threadIdx.x; s < S; s += blockDim.x) {
        int q = qb + s;
        float a = row[idx0[q]] * w0[q];
        float c = row[idx1[q]] * w1[q];
        float e = row[idx2[q]] * w2[q];
        dst[s] = (a + c) + e;             // np sum order
    }
}

extern "C" void kernel_launch(void* const* d_in, const int* in_sizes, int n_in,
                              void* d_out, int out_size, void* d_ws, size_t ws_size,
                              hipStream_t stream) {
    const float* xyz1    = (const float*)d_in[0];
    const float* xyz2    = (const float*)d_in[1];
    const float* points1 = (const float*)d_in[2];
    float* out = (float*)d_out;

    const int B = 8;
    const int N = in_sizes[0] / (3 * B);
    const int S = in_sizes[1] / (3 * B);
    const int D = in_sizes[2] / (B * N);
    const int BS = B * S;

    float* pd0 = (float*)d_ws;
    float* pd1 = pd0 + (size_t)NCHUNK * BS;
    float* pd2 = pd1 + (size_t)NCHUNK * BS;
    int*   pi0 = (int*)(pd2 + (size_t)NCHUNK * BS);
    int*   pi1 = pi0 + (size_t)NCHUNK * BS;
    int*   pi2 = pi1 + (size_t)NCHUNK * BS;
    int*   idx0 = pi2 + (size_t)NCHUNK * BS;
    int*   idx1 = idx0 + BS;
    int*   idx2 = idx1 + BS;
    float* w0   = (float*)(idx2 + BS);
    float* w1   = w0 + BS;
    float* w2   = w1 + BS;
    float* tau  = w2 + BS;

    // tau-stage buffers alias pd0..pd2 (dead before knn3_main writes them;
    // same-stream ordering guarantees tau3_merge reads first).
    float* sd0 = pd0;
    float* sd1 = pd1;
    float* sd2 = pd2;

    // Tau: 64 query-tiles x 16 sub-chunks = 1024 blocks (4/CU).
    dim3 gt(BS / QT, NSUB);
    knn3_tau<<<gt, QT, 0, stream>>>(xyz1, xyz2, B, N, S, BS, sd0, sd1, sd2);

    tau3_merge<<<(BS + 255) / 256, 256, 0, stream>>>(sd0, sd1, sd2, BS, tau);

    // Main: 64 query-tiles x 16 chunks = 1024 blocks (4/CU).
    dim3 gm(BS / QT, NCHUNK);
    knn3_main<<<gm, QT, 0, stream>>>(xyz1, xyz2, tau, B, N, S, BS,
                                     pd0, pd1, pd2, pi0, pi1, pi2);

    knn3_merge<<<(BS + 255) / 256, 256, 0, stream>>>(pd0, pd1, pd2, pi0, pi1, pi2,
                                                     BS,
                                                     idx0, idx1, idx2, w0, w1, w2);

    interp_kernel<<<B * D, 256, 0, stream>>>(points1, idx0, idx1, idx2,
                                             w0, w1, w2, out, N, S, D);
}